// Round 1
// baseline (1309.699 us; speedup 1.0000x reference)
//
#include <hip/hip_runtime.h>
#include <stdint.h>

#define D_MODEL 1024
#define H_DIM   4096
#define NE      8
#define NCAP    2560
#define NTOK    8192
#define NPAIR   (NTOK * 2)

typedef __attribute__((ext_vector_type(8))) __bf16 bf16x8;
typedef __attribute__((ext_vector_type(4))) float  f32x4;
typedef __attribute__((ext_vector_type(8))) unsigned short ushort8;

__device__ __forceinline__ unsigned short f2bf(float f) {
  union { float f; unsigned u; } v; v.f = f;
  unsigned r = v.u + 0x7fffu + ((v.u >> 16) & 1u);   // round-to-nearest-even
  return (unsigned short)(r >> 16);
}
__device__ __forceinline__ float bf2f(unsigned short s) {
  union { unsigned u; float f; } v; v.u = ((unsigned)s) << 16;
  return v.f;
}
__device__ __forceinline__ float gelu_tanh(float x) {
  // jax.nn.gelu default (approximate=True): 0.5x(1+tanh(0.79788456*(x+0.044715x^3)))
  float u = 0.7978845608028654f * (x + 0.044715f * x * x * x);
  float e = __expf(2.0f * u);
  float th = 1.0f - 2.0f / (e + 1.0f);   // saturates cleanly for |u| large
  return 0.5f * x * (1.0f + th);
}

__device__ __forceinline__ void load_lds16(const void* g, void* l) {
  __builtin_amdgcn_global_load_lds(
      (const __attribute__((address_space(1))) unsigned int*)g,
      (__attribute__((address_space(3))) unsigned int*)l, 16, 0, 0);
}

// ---------------- Router: logits, softmax, top-2, renormalized weights ------
__global__ __launch_bounds__(256) void router_kernel(
    const float* __restrict__ x, const float* __restrict__ Wr,
    int* __restrict__ pair_e, float* __restrict__ pair_w) {
  int lane = threadIdx.x & 63;
  int t = blockIdx.x * 4 + (threadIdx.x >> 6);
  float acc[NE];
#pragma unroll
  for (int e = 0; e < NE; ++e) acc[e] = 0.0f;
  const float* xr = x + (size_t)t * D_MODEL;
  for (int d = lane; d < D_MODEL; d += 64) {
    float xv = xr[d];
#pragma unroll
    for (int e = 0; e < NE; ++e) acc[e] = fmaf(xv, Wr[d * NE + e], acc[e]);
  }
#pragma unroll
  for (int off = 32; off > 0; off >>= 1) {
#pragma unroll
    for (int e = 0; e < NE; ++e) acc[e] += __shfl_down(acc[e], off, 64);
  }
  if (lane == 0) {
    int i1 = 0;
#pragma unroll
    for (int e = 1; e < NE; ++e) if (acc[e] > acc[i1]) i1 = e;
    int i2 = (i1 == 0) ? 1 : 0;
#pragma unroll
    for (int e = 0; e < NE; ++e) if (e != i1 && acc[e] > acc[i2]) i2 = e;
    float p1 = expf(acc[i1] - acc[i1]);           // = 1
    float p2 = expf(acc[i2] - acc[i1]);
    float inv = 1.0f / (p1 + p2);
    pair_e[t * 2]     = i1;  pair_e[t * 2 + 1] = i2;
    pair_w[t * 2]     = p1 * inv;
    pair_w[t * 2 + 1] = p2 * inv;
  }
}

// ------------- Slot assignment: pair-ordered cumsum, capacity drop ----------
__global__ void assign_kernel(const int* __restrict__ pair_e,
                              const float* __restrict__ pair_w,
                              int* __restrict__ pair_dest,
                              int* __restrict__ slot_token,
                              float* __restrict__ slot_w,
                              int* __restrict__ counts) {
  int lane = threadIdx.x;       // single wave of 64
  int run[NE];
#pragma unroll
  for (int e = 0; e < NE; ++e) run[e] = 0;
  unsigned long long below = (lane == 63) ? 0x7fffffffffffffffull
                                          : ((1ull << lane) - 1ull);
  for (int base = 0; base < NPAIR; base += 64) {
    int i = base + lane;
    int e = pair_e[i];
    int pos = 0;
#pragma unroll
    for (int ex = 0; ex < NE; ++ex) {
      unsigned long long m = __ballot(e == ex);
      if (e == ex) pos = run[ex] + __popcll(m & below);
      run[ex] += __popcll(m);
    }
    bool keep = pos < NCAP;
    int dest = keep ? (e * NCAP + pos) : (NE * NCAP);
    pair_dest[i] = dest;
    if (keep) {
      slot_token[dest] = i >> 1;
      slot_w[dest] = pair_w[i];
    }
  }
  if (lane == 0) {
#pragma unroll
    for (int e = 0; e < NE; ++e) counts[e] = run[e] < NCAP ? run[e] : NCAP;
  }
}

// --------------- Dispatch: gather x rows -> bf16 expert buffer --------------
__global__ __launch_bounds__(64) void dispatch_kernel(
    const float* __restrict__ x, const int* __restrict__ pair_dest,
    unsigned short* __restrict__ Xd) {
  int i = blockIdx.x;
  int dest = pair_dest[i];
  if (dest >= NE * NCAP) return;
  int lane = threadIdx.x;
  int t = i >> 1;
  const float4* xr = (const float4*)(x + (size_t)t * D_MODEL);
  ushort4* dr = (ushort4*)(Xd + (size_t)dest * D_MODEL);
#pragma unroll
  for (int c = 0; c < 4; ++c) {
    float4 v = xr[lane + c * 64];
    ushort4 o;
    o.x = f2bf(v.x); o.y = f2bf(v.y); o.z = f2bf(v.z); o.w = f2bf(v.w);
    dr[lane + c * 64] = o;
  }
}

// ------------- Transpose + f32->bf16 convert: [E][R][C] -> [E][C][R] --------
__global__ __launch_bounds__(256) void transpose_cvt(
    const float* __restrict__ src, unsigned short* __restrict__ dst,
    int R, int C) {
  __shared__ float tile[64][65];
  int e = blockIdx.z;
  int c0 = blockIdx.x * 64, r0 = blockIdx.y * 64;
  int col = threadIdx.x & 63, rr = threadIdx.x >> 6;
  const float* s = src + (size_t)e * R * C;
#pragma unroll
  for (int it = 0; it < 16; ++it) {
    int row = it * 4 + rr;
    tile[row][col] = s[(size_t)(r0 + row) * C + c0 + col];
  }
  __syncthreads();
  unsigned short* d = dst + (size_t)e * R * C;
#pragma unroll
  for (int it = 0; it < 16; ++it) {
    int crow = it * 4 + rr;
    d[(size_t)(c0 + crow) * R + r0 + col] = f2bf(tile[col][crow]);
  }
}

// --------------------------- Grouped MFMA GEMM ------------------------------
// A: [E][M][K] bf16 row-major; B: [E][N][K] bf16 (i.e. B^T, k-contiguous).
// mode 0: h_out = gelu(A@B + bias) as bf16 [E][M][N]
// mode 1: atomicAdd into y_out[token] of slot_w * (A@B + bias), via slot_token
__global__ __launch_bounds__(256, 2) void moe_gemm(
    const unsigned short* __restrict__ Abase,
    const unsigned short* __restrict__ Bbase,
    const float* __restrict__ bias,
    unsigned short* __restrict__ h_out,
    float* __restrict__ y_out,
    const int* __restrict__ counts,
    const int* __restrict__ slot_token,
    const float* __restrict__ slot_w,
    int M, int N, int K, int mode) {
  __shared__ char smem[32768];          // As 16KB | Bs 16KB, reused as C-tile
  const int e = blockIdx.z;
  const int m0 = blockIdx.x * 128;
  const int n0 = blockIdx.y * 128;
  const int cnt = counts[e];
  if (m0 >= cnt) return;

  const int tid = threadIdx.x;
  const int lane = tid & 63;
  const int wid = tid >> 6;
  const int wm = (wid & 1) * 64;
  const int wn = (wid >> 1) * 64;

  const unsigned short* A = Abase + (size_t)e * M * K;
  const unsigned short* B = Bbase + (size_t)e * N * K;

  f32x4 acc[4][4];
  f32x4 zero = {0.f, 0.f, 0.f, 0.f};
#pragma unroll
  for (int i = 0; i < 4; ++i)
#pragma unroll
    for (int j = 0; j < 4; ++j) acc[i][j] = zero;

  char* As = smem;
  char* Bs = smem + 16384;

  // Per-thread staging chunk geometry (constant over K loop)
  int ci[4], srow[4], sgc[4];
#pragma unroll
  for (int c = 0; c < 4; ++c) {
    ci[c] = c * 256 + wid * 64 + lane;
    srow[c] = ci[c] >> 3;
    sgc[c] = (ci[c] & 7) ^ (srow[c] & 7);   // XOR swizzle on global chunk
  }

  const int KT = K >> 6;
  for (int kt = 0; kt < KT; ++kt) {
    const int k0 = kt << 6;
#pragma unroll
    for (int c = 0; c < 4; ++c) {
      const unsigned short* ga = A + (size_t)(m0 + srow[c]) * K + k0 + sgc[c] * 8;
      load_lds16(ga, As + (c * 256 + wid * 64) * 16);
      const unsigned short* gb = B + (size_t)(n0 + srow[c]) * K + k0 + sgc[c] * 8;
      load_lds16(gb, Bs + (c * 256 + wid * 64) * 16);
    }
    __syncthreads();   // compiler drains vmcnt before barrier
#pragma unroll
    for (int kk = 0; kk < 2; ++kk) {
      bf16x8 af[4], bfr[4];
      int lc = kk * 4 + (lane >> 4);
#pragma unroll
      for (int f = 0; f < 4; ++f) {
        int ar = wm + f * 16 + (lane & 15);
        af[f] = *(const bf16x8*)(As + ar * 128 + ((lc ^ (ar & 7)) * 16));
        int br = wn + f * 16 + (lane & 15);
        bfr[f] = *(const bf16x8*)(Bs + br * 128 + ((lc ^ (br & 7)) * 16));
      }
#pragma unroll
      for (int i = 0; i < 4; ++i)
#pragma unroll
        for (int j = 0; j < 4; ++j)
          acc[i][j] = __builtin_amdgcn_mfma_f32_16x16x32_bf16(
              af[i], bfr[j], acc[i][j], 0, 0, 0);
    }
    __syncthreads();
  }

  // ---- Epilogue: stage C tile (bf16) in LDS, then coalesced write/scatter --
  const float* be = bias + (size_t)e * N;
#pragma unroll
  for (int i = 0; i < 4; ++i) {
    int rbase = wm + i * 16 + (lane >> 4) * 4;
#pragma unroll
    for (int j = 0; j < 4; ++j) {
      int col = wn + j * 16 + (lane & 15);
      float bv = be[n0 + col];
#pragma unroll
      for (int r = 0; r < 4; ++r) {
        float xv = acc[i][j][r] + bv;
        if (mode == 0) xv = gelu_tanh(xv);
        *(unsigned short*)(smem + (rbase + r) * 256 + col * 2) = f2bf(xv);
      }
    }
  }
  __syncthreads();
  const int r16 = tid >> 4, c16 = tid & 15;
  if (mode == 0) {
#pragma unroll
    for (int it = 0; it < 8; ++it) {
      int row = it * 16 + r16;
      ushort8 v = *(const ushort8*)(smem + row * 256 + c16 * 16);
      *(ushort8*)(h_out + ((size_t)e * M + m0 + row) * N + n0 + c16 * 8) = v;
    }
  } else {
#pragma unroll
    for (int it = 0; it < 8; ++it) {
      int row = it * 16 + r16;
      int slot = e * M + m0 + row;
      int t = slot_token[slot];
      if (t >= 0) {
        float w = slot_w[slot];
        ushort8 v = *(const ushort8*)(smem + row * 256 + c16 * 16);
        float* dst = y_out + (size_t)t * D_MODEL + n0 + c16 * 8;
#pragma unroll
        for (int jj = 0; jj < 8; ++jj) atomicAdd(dst + jj, w * bf2f(v[jj]));
      }
    }
  }
}

// ---------------------------------------------------------------------------
extern "C" void kernel_launch(void* const* d_in, const int* in_sizes, int n_in,
                              void* d_out, int out_size, void* d_ws, size_t ws_size,
                              hipStream_t stream) {
  const float* x  = (const float*)d_in[0];
  const float* Wr = (const float*)d_in[1];
  const float* W1 = (const float*)d_in[2];
  const float* b1 = (const float*)d_in[3];
  const float* W2 = (const float*)d_in[4];
  const float* b2 = (const float*)d_in[5];
  float* out = (float*)d_out;

  char* ws = (char*)d_ws;
  // ws layout (bytes)
  unsigned short* W1T   = (unsigned short*)(ws + 0);            // 67,108,864
  unsigned short* W2T   = (unsigned short*)(ws + 67108864);     // 67,108,864
  unsigned short* Xd    = (unsigned short*)(ws + 134217728);    // 41,943,040
  unsigned short* Hbuf  = (unsigned short*)(ws + 176160768);    // 167,772,160
  int*   pair_e     = (int*)(ws + 343932928);                   // 65,536
  float* pair_w     = (float*)(ws + 343998464);                 // 65,536
  int*   pair_dest  = (int*)(ws + 344064000);                   // 65,536
  int*   slot_token = (int*)(ws + 344129536);                   // 81,920
  float* slot_w     = (float*)(ws + 344211456);                 // 81,920
  int*   counts     = (int*)(ws + 344293376);                   // 32

  hipMemsetAsync(d_out, 0, (size_t)out_size * sizeof(float), stream);
  hipMemsetAsync(Xd, 0, (size_t)NE * NCAP * D_MODEL * 2, stream);
  hipMemsetAsync(slot_token, 0xFF, (size_t)NE * NCAP * 4, stream);

  // Weight transpose+convert: W1 [E][D][H] -> W1T [E][H][D]; W2 [E][H][D] -> W2T [E][D][H]
  transpose_cvt<<<dim3(H_DIM / 64, D_MODEL / 64, NE), 256, 0, stream>>>(W1, W1T, D_MODEL, H_DIM);
  transpose_cvt<<<dim3(D_MODEL / 64, H_DIM / 64, NE), 256, 0, stream>>>(W2, W2T, H_DIM, D_MODEL);

  router_kernel<<<NTOK / 4, 256, 0, stream>>>(x, Wr, pair_e, pair_w);
  assign_kernel<<<1, 64, 0, stream>>>(pair_e, pair_w, pair_dest, slot_token, slot_w, counts);
  dispatch_kernel<<<NPAIR, 64, 0, stream>>>(x, pair_dest, Xd);

  // GEMM1: h = gelu(Xd @ W1 + b1)   M=CAP N=H K=D
  moe_gemm<<<dim3(NCAP / 128, H_DIM / 128, NE), 256, 0, stream>>>(
      Xd, W1T, b1, Hbuf, nullptr, counts, nullptr, nullptr,
      NCAP, H_DIM, D_MODEL, 0);
  // GEMM2: y += w * (h @ W2 + b2)   M=CAP N=D K=H
  moe_gemm<<<dim3(NCAP / 128, D_MODEL / 128, NE), 256, 0, stream>>>(
      Hbuf, W2T, b2, nullptr, out, counts, slot_token, slot_w,
      NCAP, D_MODEL, H_DIM, 1);
}

// Round 2
// 890.473 us; speedup vs baseline: 1.4708x; 1.4708x over previous
//
#include <hip/hip_runtime.h>
#include <stdint.h>

#define D_MODEL 1024
#define H_DIM   4096
#define NE      8
#define NCAP    2560
#define NTOK    8192
#define NPAIR   (NTOK * 2)

typedef __attribute__((ext_vector_type(8))) __bf16 bf16x8;
typedef __attribute__((ext_vector_type(4))) float  f32x4;
typedef __attribute__((ext_vector_type(8))) unsigned short ushort8;

__device__ __forceinline__ unsigned short f2bf(float f) {
  union { float f; unsigned u; } v; v.f = f;
  unsigned r = v.u + 0x7fffu + ((v.u >> 16) & 1u);   // round-to-nearest-even
  return (unsigned short)(r >> 16);
}
__device__ __forceinline__ float bf2f(unsigned short s) {
  union { unsigned u; float f; } v; v.u = ((unsigned)s) << 16;
  return v.f;
}
__device__ __forceinline__ float gelu_tanh(float x) {
  float u = 0.7978845608028654f * (x + 0.044715f * x * x * x);
  float e = __expf(2.0f * u);
  float th = 1.0f - 2.0f / (e + 1.0f);
  return 0.5f * x * (1.0f + th);
}
__device__ __forceinline__ void load_lds16(const void* g, void* l) {
  __builtin_amdgcn_global_load_lds(
      (const __attribute__((address_space(1))) unsigned int*)g,
      (__attribute__((address_space(3))) unsigned int*)l, 16, 0, 0);
}

// ---------------- Router ----------------------------------------------------
__global__ __launch_bounds__(256) void router_kernel(
    const float* __restrict__ x, const float* __restrict__ Wr,
    int* __restrict__ pair_e, float* __restrict__ pair_w) {
  int lane = threadIdx.x & 63;
  int t = blockIdx.x * 4 + (threadIdx.x >> 6);
  float acc[NE];
#pragma unroll
  for (int e = 0; e < NE; ++e) acc[e] = 0.0f;
  const float* xr = x + (size_t)t * D_MODEL;
  for (int d = lane; d < D_MODEL; d += 64) {
    float xv = xr[d];
#pragma unroll
    for (int e = 0; e < NE; ++e) acc[e] = fmaf(xv, Wr[d * NE + e], acc[e]);
  }
#pragma unroll
  for (int off = 32; off > 0; off >>= 1) {
#pragma unroll
    for (int e = 0; e < NE; ++e) acc[e] += __shfl_down(acc[e], off, 64);
  }
  if (lane == 0) {
    int i1 = 0;
#pragma unroll
    for (int e = 1; e < NE; ++e) if (acc[e] > acc[i1]) i1 = e;
    int i2 = (i1 == 0) ? 1 : 0;
#pragma unroll
    for (int e = 0; e < NE; ++e) if (e != i1 && acc[e] > acc[i2]) i2 = e;
    float p2 = expf(acc[i2] - acc[i1]);
    float inv = 1.0f / (1.0f + p2);
    pair_e[t * 2]     = i1;  pair_e[t * 2 + 1] = i2;
    pair_w[t * 2]     = inv;
    pair_w[t * 2 + 1] = p2 * inv;
  }
}

// ------------- Slot assignment (pair-ordered cumsum, capacity drop) ---------
__global__ void assign_kernel(const int* __restrict__ pair_e,
                              int* __restrict__ pair_dest,
                              int* __restrict__ counts) {
  int lane = threadIdx.x;       // single wave of 64
  int run[NE];
#pragma unroll
  for (int e = 0; e < NE; ++e) run[e] = 0;
  unsigned long long below = (lane == 63) ? 0x7fffffffffffffffull
                                          : ((1ull << lane) - 1ull);
  for (int base = 0; base < NPAIR; base += 64) {
    int i = base + lane;
    int e = pair_e[i];
    int pos = 0;
#pragma unroll
    for (int ex = 0; ex < NE; ++ex) {
      unsigned long long m = __ballot(e == ex);
      if (e == ex) pos = run[ex] + __popcll(m & below);
      run[ex] += __popcll(m);
    }
    bool keep = pos < NCAP;
    pair_dest[i] = keep ? (e * NCAP + pos) : (NE * NCAP);
  }
  if (lane == 0) {
#pragma unroll
    for (int e = 0; e < NE; ++e) counts[e] = run[e] < NCAP ? run[e] : NCAP;
  }
}

// --------------- Dispatch: gather x rows -> bf16 expert buffer --------------
__global__ __launch_bounds__(64) void dispatch_kernel(
    const float* __restrict__ x, const int* __restrict__ pair_dest,
    unsigned short* __restrict__ Xd) {
  int i = blockIdx.x;
  int dest = pair_dest[i];
  if (dest >= NE * NCAP) return;
  int lane = threadIdx.x;
  int t = i >> 1;
  const float4* xr = (const float4*)(x + (size_t)t * D_MODEL);
  ushort4* dr = (ushort4*)(Xd + (size_t)dest * D_MODEL);
#pragma unroll
  for (int c = 0; c < 4; ++c) {
    float4 v = xr[lane + c * 64];
    ushort4 o;
    o.x = f2bf(v.x); o.y = f2bf(v.y); o.z = f2bf(v.z); o.w = f2bf(v.w);
    dr[lane + c * 64] = o;
  }
}

// ------------- Transpose + f32->bf16 convert: [E][R][C] -> [E][C][R] --------
__global__ __launch_bounds__(256) void transpose_cvt(
    const float* __restrict__ src, unsigned short* __restrict__ dst,
    int R, int C) {
  __shared__ float tile[64][65];
  int e = blockIdx.z;
  int c0 = blockIdx.x * 64, r0 = blockIdx.y * 64;
  int col = threadIdx.x & 63, rr = threadIdx.x >> 6;
  const float* s = src + (size_t)e * R * C;
#pragma unroll
  for (int it = 0; it < 16; ++it) {
    int row = it * 4 + rr;
    tile[row][col] = s[(size_t)(r0 + row) * C + c0 + col];
  }
  __syncthreads();
  unsigned short* d = dst + (size_t)e * R * C;
#pragma unroll
  for (int it = 0; it < 16; ++it) {
    int crow = it * 4 + rr;
    d[(size_t)(c0 + crow) * R + r0 + col] = f2bf(tile[col][crow]);
  }
}

// --------------------------- Grouped MFMA GEMM ------------------------------
// A: [E][M][K] bf16 row-major; B: [E][N][K] bf16 (B^T, k-contiguous).
// Cout = (gelu?)(A@B + bias) as bf16 [E][M][N].
// Double-buffered LDS pipeline + 4x4 supertile block swizzle for L2 locality.
__global__ __launch_bounds__(256, 2) void moe_gemm(
    const unsigned short* __restrict__ Abase,
    const unsigned short* __restrict__ Bbase,
    const float* __restrict__ bias,
    unsigned short* __restrict__ Cout,
    const int* __restrict__ counts,
    int M, int N, int K, int NBM, int do_gelu) {
  __shared__ char smem[65536];          // buf0: As0|Bs0 (32KB), buf1: As1|Bs1
  const int e = blockIdx.z;
  // 4x4 supertile swizzle: consecutive blocks share 4 A-slabs + 4 B-panels
  int r = blockIdx.x;
  int grp = r >> 4, lid = r & 15;
  int mg = NBM >> 2;
  int gm = grp % mg, gn = grp / mg;
  const int m0 = (gm * 4 + (lid & 3)) * 128;
  const int n0 = (gn * 4 + (lid >> 2)) * 128;
  const int cnt = counts[e];
  if (m0 >= cnt) return;

  const int tid = threadIdx.x;
  const int lane = tid & 63;
  const int wid = tid >> 6;
  const int wm = (wid & 1) * 64;
  const int wn = (wid >> 1) * 64;

  const unsigned short* A = Abase + (size_t)e * M * K;
  const unsigned short* B = Bbase + (size_t)e * N * K;

  f32x4 acc[4][4];
  f32x4 zero = {0.f, 0.f, 0.f, 0.f};
#pragma unroll
  for (int i = 0; i < 4; ++i)
#pragma unroll
    for (int j = 0; j < 4; ++j) acc[i][j] = zero;

  char* As0 = smem;
  char* Bs0 = smem + 16384;
  char* As1 = smem + 32768;
  char* Bs1 = smem + 49152;

  // Per-thread staging geometry (XOR-swizzled chunk within row)
  const unsigned short* ga[4];
  const unsigned short* gb[4];
  int ldso[4];
#pragma unroll
  for (int c = 0; c < 4; ++c) {
    int ci = c * 256 + wid * 64 + lane;
    int srow = ci >> 3;
    int sgc = (ci & 7) ^ (srow & 7);
    ga[c] = A + (size_t)(m0 + srow) * K + sgc * 8;
    gb[c] = B + (size_t)(n0 + srow) * K + sgc * 8;
    ldso[c] = (c * 256 + wid * 64) * 16;
  }

  auto stage = [&](char* As, char* Bs) {
#pragma unroll
    for (int c = 0; c < 4; ++c) {
      load_lds16(ga[c], As + ldso[c]);
      ga[c] += 64;
      load_lds16(gb[c], Bs + ldso[c]);
      gb[c] += 64;
    }
  };
  auto compute = [&](char* As, char* Bs) {
#pragma unroll
    for (int kk = 0; kk < 2; ++kk) {
      bf16x8 af[4], bfr[4];
      int lc = kk * 4 + (lane >> 4);
#pragma unroll
      for (int f = 0; f < 4; ++f) {
        int ar = wm + f * 16 + (lane & 15);
        af[f] = *(const bf16x8*)(As + ar * 128 + ((lc ^ (ar & 7)) * 16));
        int br = wn + f * 16 + (lane & 15);
        bfr[f] = *(const bf16x8*)(Bs + br * 128 + ((lc ^ (br & 7)) * 16));
      }
#pragma unroll
      for (int i = 0; i < 4; ++i)
#pragma unroll
        for (int j = 0; j < 4; ++j)
          acc[i][j] = __builtin_amdgcn_mfma_f32_16x16x32_bf16(
              af[i], bfr[j], acc[i][j], 0, 0, 0);
    }
  };

  const int KT = K >> 6;                 // 16 or 64 (even)
  stage(As0, Bs0);                       // prologue: tile 0 in flight
  for (int kt = 0; kt < KT; kt += 2) {
    __syncthreads();                     // drains tile kt (overlapped w/ prev compute)
    if (kt + 1 < KT) stage(As1, Bs1);    // tile kt+1 in flight during compute kt
    compute(As0, Bs0);
    __syncthreads();                     // drains tile kt+1
    if (kt + 2 < KT) stage(As0, Bs0);
    compute(As1, Bs1);
  }

  // ---- Epilogue: stage bf16 C tile in LDS (buf0 region), coalesced store --
  const float* be = bias + (size_t)e * N;
#pragma unroll
  for (int i = 0; i < 4; ++i) {
    int rbase = wm + i * 16 + (lane >> 4) * 4;
#pragma unroll
    for (int j = 0; j < 4; ++j) {
      int col = wn + j * 16 + (lane & 15);
      float bv = be[n0 + col];
#pragma unroll
      for (int r2 = 0; r2 < 4; ++r2) {
        float xv = acc[i][j][r2] + bv;
        if (do_gelu) xv = gelu_tanh(xv);
        *(unsigned short*)(smem + (rbase + r2) * 256 + col * 2) = f2bf(xv);
      }
    }
  }
  __syncthreads();
  const int r16 = tid >> 4, c16 = tid & 15;
#pragma unroll
  for (int it = 0; it < 8; ++it) {
    int row = it * 16 + r16;
    ushort8 v = *(const ushort8*)(smem + row * 256 + c16 * 16);
    *(ushort8*)(Cout + ((size_t)e * M + m0 + row) * N + n0 + c16 * 8) = v;
  }
}

// --------------- Combine: y[t] = sum_k w_k * Ebuf[dest_k] -------------------
__global__ __launch_bounds__(256) void combine_kernel(
    const unsigned short* __restrict__ Ebuf,
    const int* __restrict__ pair_dest,
    const float* __restrict__ pair_w,
    float* __restrict__ out) {
  int t = blockIdx.x;
  int d0 = threadIdx.x * 4;
  float4 r = {0.f, 0.f, 0.f, 0.f};
#pragma unroll
  for (int k = 0; k < 2; ++k) {
    int dest = pair_dest[t * 2 + k];
    if (dest < NE * NCAP) {
      float w = pair_w[t * 2 + k];
      ushort4 v = *(const ushort4*)(Ebuf + (size_t)dest * D_MODEL + d0);
      r.x += w * bf2f(v.x); r.y += w * bf2f(v.y);
      r.z += w * bf2f(v.z); r.w += w * bf2f(v.w);
    }
  }
  *(float4*)(out + (size_t)t * D_MODEL + d0) = r;
}

// ---------------------------------------------------------------------------
extern "C" void kernel_launch(void* const* d_in, const int* in_sizes, int n_in,
                              void* d_out, int out_size, void* d_ws, size_t ws_size,
                              hipStream_t stream) {
  const float* x  = (const float*)d_in[0];
  const float* Wr = (const float*)d_in[1];
  const float* W1 = (const float*)d_in[2];
  const float* b1 = (const float*)d_in[3];
  const float* W2 = (const float*)d_in[4];
  const float* b2 = (const float*)d_in[5];
  float* out = (float*)d_out;

  char* ws = (char*)d_ws;
  unsigned short* W1T  = (unsigned short*)(ws + 0);            // 64 MB
  unsigned short* W2T  = (unsigned short*)(ws + 67108864);     // 64 MB
  unsigned short* Xd   = (unsigned short*)(ws + 134217728);    // 40 MB
  unsigned short* Ebuf = Xd;   // aliased: Xd dead after GEMM1, same size
  unsigned short* Hbuf = (unsigned short*)(ws + 176160768);    // 160 MB
  int*   pair_e    = (int*)(ws + 343932928);
  float* pair_w    = (float*)(ws + 343998464);
  int*   pair_dest = (int*)(ws + 344064000);
  int*   counts    = (int*)(ws + 344129536);

  // W1 [E][D][H] -> W1T [E][H][D]; W2 [E][H][D] -> W2T [E][D][H]
  transpose_cvt<<<dim3(H_DIM / 64, D_MODEL / 64, NE), 256, 0, stream>>>(W1, W1T, D_MODEL, H_DIM);
  transpose_cvt<<<dim3(D_MODEL / 64, H_DIM / 64, NE), 256, 0, stream>>>(W2, W2T, H_DIM, D_MODEL);

  router_kernel<<<NTOK / 4, 256, 0, stream>>>(x, Wr, pair_e, pair_w);
  assign_kernel<<<1, 64, 0, stream>>>(pair_e, pair_dest, counts);
  dispatch_kernel<<<NPAIR, 64, 0, stream>>>(x, pair_dest, Xd);

  // GEMM1: h = gelu(Xd @ W1 + b1)   M=CAP N=H K=D   (NBM=20, NBN=32)
  moe_gemm<<<dim3((NCAP / 128) * (H_DIM / 128), 1, NE), 256, 0, stream>>>(
      Xd, W1T, b1, Hbuf, counts, NCAP, H_DIM, D_MODEL, NCAP / 128, 1);
  // GEMM2: Ebuf = h @ W2 + b2       M=CAP N=D K=H   (NBM=20, NBN=8)
  moe_gemm<<<dim3((NCAP / 128) * (D_MODEL / 128), 1, NE), 256, 0, stream>>>(
      Hbuf, W2T, b2, Ebuf, counts, NCAP, D_MODEL, H_DIM, NCAP / 128, 0);

  combine_kernel<<<NTOK, 256, 0, stream>>>(Ebuf, pair_dest, pair_w, out);
}

// Round 4
// 770.084 us; speedup vs baseline: 1.7007x; 1.1563x over previous
//
#include <hip/hip_runtime.h>
#include <stdint.h>

#define D_MODEL 1024
#define H_DIM   4096
#define NE      8
#define NCAP    2560
#define NTOK    8192
#define NPAIR   (NTOK * 2)

typedef __attribute__((ext_vector_type(8))) __bf16 bf16x8;
typedef __attribute__((ext_vector_type(4))) float  f32x4;
typedef __attribute__((ext_vector_type(8))) unsigned short ushort8;

__device__ __forceinline__ unsigned short f2bf(float f) {
  union { float f; unsigned u; } v; v.f = f;
  unsigned r = v.u + 0x7fffu + ((v.u >> 16) & 1u);   // round-to-nearest-even
  return (unsigned short)(r >> 16);
}
__device__ __forceinline__ float bf2f(unsigned short s) {
  union { unsigned u; float f; } v; v.u = ((unsigned)s) << 16;
  return v.f;
}
__device__ __forceinline__ float gelu_tanh(float x) {
  float u = 0.7978845608028654f * (x + 0.044715f * x * x * x);
  float e = __expf(2.0f * u);
  float th = 1.0f - 2.0f / (e + 1.0f);
  return 0.5f * x * (1.0f + th);
}
__device__ __forceinline__ void load_lds16(const void* g, void* l) {
  __builtin_amdgcn_global_load_lds(
      (const __attribute__((address_space(1))) unsigned int*)g,
      (__attribute__((address_space(3))) unsigned int*)l, 16, 0, 0);
}

// ---------------- Router ----------------------------------------------------
__global__ __launch_bounds__(256) void router_kernel(
    const float* __restrict__ x, const float* __restrict__ Wr,
    int* __restrict__ pair_e, float* __restrict__ pair_w) {
  int lane = threadIdx.x & 63;
  int t = blockIdx.x * 4 + (threadIdx.x >> 6);
  float acc[NE];
#pragma unroll
  for (int e = 0; e < NE; ++e) acc[e] = 0.0f;
  const float* xr = x + (size_t)t * D_MODEL;
  for (int d = lane; d < D_MODEL; d += 64) {
    float xv = xr[d];
#pragma unroll
    for (int e = 0; e < NE; ++e) acc[e] = fmaf(xv, Wr[d * NE + e], acc[e]);
  }
#pragma unroll
  for (int off = 32; off > 0; off >>= 1) {
#pragma unroll
    for (int e = 0; e < NE; ++e) acc[e] += __shfl_down(acc[e], off, 64);
  }
  if (lane == 0) {
    int i1 = 0;
#pragma unroll
    for (int e = 1; e < NE; ++e) if (acc[e] > acc[i1]) i1 = e;
    int i2 = (i1 == 0) ? 1 : 0;
#pragma unroll
    for (int e = 0; e < NE; ++e) if (e != i1 && acc[e] > acc[i2]) i2 = e;
    float p2 = expf(acc[i2] - acc[i1]);
    float inv = 1.0f / (1.0f + p2);
    pair_e[t * 2]     = i1;  pair_e[t * 2 + 1] = i2;
    pair_w[t * 2]     = inv;
    pair_w[t * 2 + 1] = p2 * inv;
  }
}

// ------- Slot assignment: parallel pair-ordered cumsum (exact ref order) ----
// 1024 threads x 16 pairs each. wave shuffle scan + cross-wave LDS scan.
__global__ __launch_bounds__(1024) void assign_kernel(
    const int* __restrict__ pair_e, int* __restrict__ pair_dest,
    int* __restrict__ counts) {
  __shared__ int wtot[16][NE];
  const int tid = threadIdx.x;
  const int lane = tid & 63, w = tid >> 6;

  int ids[16];
  const int4* pe = (const int4*)(pair_e + tid * 16);
#pragma unroll
  for (int q = 0; q < 4; ++q) {
    int4 v = pe[q];
    ids[q * 4 + 0] = v.x; ids[q * 4 + 1] = v.y;
    ids[q * 4 + 2] = v.z; ids[q * 4 + 3] = v.w;
  }
  int c[NE];
#pragma unroll
  for (int e = 0; e < NE; ++e) c[e] = 0;
#pragma unroll
  for (int j = 0; j < 16; ++j) c[ids[j]]++;

  // wave-level inclusive scan per expert
  int incl[NE];
#pragma unroll
  for (int e = 0; e < NE; ++e) incl[e] = c[e];
#pragma unroll
  for (int d = 1; d < 64; d <<= 1) {
#pragma unroll
    for (int e = 0; e < NE; ++e) {
      int u = __shfl_up(incl[e], d, 64);
      if (lane >= d) incl[e] += u;
    }
  }
  if (lane == 63) {
#pragma unroll
    for (int e = 0; e < NE; ++e) wtot[w][e] = incl[e];
  }
  __syncthreads();
  if (tid < NE) {
    int run = 0;
#pragma unroll
    for (int ww = 0; ww < 16; ++ww) {
      int t2 = wtot[ww][tid];
      wtot[ww][tid] = run;
      run += t2;
    }
    counts[tid] = run < NCAP ? run : NCAP;
  }
  __syncthreads();

  int off[NE];
#pragma unroll
  for (int e = 0; e < NE; ++e) off[e] = wtot[w][e] + incl[e] - c[e];
#pragma unroll
  for (int j = 0; j < 16; ++j) {
    int e = ids[j];
    int pos = off[e]++;
    pair_dest[tid * 16 + j] = (pos < NCAP) ? (e * NCAP + pos) : (NE * NCAP);
  }
}

// --------------- Dispatch: gather x rows -> bf16 expert buffer --------------
__global__ __launch_bounds__(64) void dispatch_kernel(
    const float* __restrict__ x, const int* __restrict__ pair_dest,
    unsigned short* __restrict__ Xd) {
  int i = blockIdx.x;
  int dest = pair_dest[i];
  if (dest >= NE * NCAP) return;
  int lane = threadIdx.x;
  int t = i >> 1;
  const float4* xr = (const float4*)(x + (size_t)t * D_MODEL);
  ushort4* dr = (ushort4*)(Xd + (size_t)dest * D_MODEL);
#pragma unroll
  for (int c = 0; c < 4; ++c) {
    float4 v = xr[lane + c * 64];
    ushort4 o;
    o.x = f2bf(v.x); o.y = f2bf(v.y); o.z = f2bf(v.z); o.w = f2bf(v.w);
    dr[lane + c * 64] = o;
  }
}

// ------------- Transpose + f32->bf16 convert: [E][R][C] -> [E][C][R] --------
__global__ __launch_bounds__(256) void transpose_cvt(
    const float* __restrict__ src, unsigned short* __restrict__ dst,
    int R, int C) {
  __shared__ float tile[64][65];
  int e = blockIdx.z;
  int c0 = blockIdx.x * 64, r0 = blockIdx.y * 64;
  int col = threadIdx.x & 63, rr = threadIdx.x >> 6;
  const float* s = src + (size_t)e * R * C;
#pragma unroll
  for (int it = 0; it < 16; ++it) {
    int row = it * 4 + rr;
    tile[row][col] = s[(size_t)(r0 + row) * C + c0 + col];
  }
  __syncthreads();
  unsigned short* d = dst + (size_t)e * R * C;
#pragma unroll
  for (int it = 0; it < 16; ++it) {
    int crow = it * 4 + rr;
    d[(size_t)(c0 + crow) * R + r0 + col] = f2bf(tile[col][crow]);
  }
}

// --------------------------- Grouped MFMA GEMM ------------------------------
// A: [E][M][K] bf16 row-major; B: [E][N][K] bf16 (B^T, k-contiguous).
// Cout = (gelu?)(A@B + bias) as bf16 [E][M][N].
// Single 32KB LDS buffer (m97 structure) -> 5 blocks/CU; 4x4 supertile swizzle.
__global__ __launch_bounds__(256, 4) void moe_gemm(
    const unsigned short* __restrict__ Abase,
    const unsigned short* __restrict__ Bbase,
    const float* __restrict__ bias,
    unsigned short* __restrict__ Cout,
    const int* __restrict__ counts,
    int M, int N, int K, int NBM, int do_gelu) {
  __shared__ char smem[32768];          // As 16KB | Bs 16KB; reused for C tile
  const int e = blockIdx.z;
  int r = blockIdx.x;
  int grp = r >> 4, lid = r & 15;
  int mg = NBM >> 2;
  int gm = grp % mg, gn = grp / mg;
  const int m0 = (gm * 4 + (lid & 3)) * 128;
  const int n0 = (gn * 4 + (lid >> 2)) * 128;
  const int cnt = counts[e];
  if (m0 >= cnt) return;

  const int tid = threadIdx.x;
  const int lane = tid & 63;
  const int wid = tid >> 6;
  const int wm = (wid & 1) * 64;
  const int wn = (wid >> 1) * 64;

  const unsigned short* A = Abase + (size_t)e * M * K;
  const unsigned short* B = Bbase + (size_t)e * N * K;

  f32x4 acc[4][4];
  f32x4 zero = {0.f, 0.f, 0.f, 0.f};
#pragma unroll
  for (int i = 0; i < 4; ++i)
#pragma unroll
    for (int j = 0; j < 4; ++j) acc[i][j] = zero;

  char* As = smem;
  char* Bs = smem + 16384;

  const unsigned short* ga[4];
  const unsigned short* gb[4];
  int ldso[4];
#pragma unroll
  for (int c = 0; c < 4; ++c) {
    int ci = c * 256 + wid * 64 + lane;
    int srow = ci >> 3;
    int sgc = (ci & 7) ^ (srow & 7);    // XOR swizzle on global chunk
    ga[c] = A + (size_t)(m0 + srow) * K + sgc * 8;
    gb[c] = B + (size_t)(n0 + srow) * K + sgc * 8;
    ldso[c] = (c * 256 + wid * 64) * 16;
  }

  const int KT = K >> 6;
  for (int kt = 0; kt < KT; ++kt) {
#pragma unroll
    for (int c = 0; c < 4; ++c) {
      load_lds16(ga[c], As + ldso[c]);
      ga[c] += 64;
      load_lds16(gb[c], Bs + ldso[c]);
      gb[c] += 64;
    }
    __syncthreads();
#pragma unroll
    for (int kk = 0; kk < 2; ++kk) {
      bf16x8 af[4], bfr[4];
      int lc = kk * 4 + (lane >> 4);
#pragma unroll
      for (int f = 0; f < 4; ++f) {
        int ar = wm + f * 16 + (lane & 15);
        af[f] = *(const bf16x8*)(As + ar * 128 + ((lc ^ (ar & 7)) * 16));
        int br = wn + f * 16 + (lane & 15);
        bfr[f] = *(const bf16x8*)(Bs + br * 128 + ((lc ^ (br & 7)) * 16));
      }
#pragma unroll
      for (int i = 0; i < 4; ++i)
#pragma unroll
        for (int j = 0; j < 4; ++j)
          acc[i][j] = __builtin_amdgcn_mfma_f32_16x16x32_bf16(
              af[i], bfr[j], acc[i][j], 0, 0, 0);
    }
    __syncthreads();
  }

  // ---- Epilogue: stage bf16 C tile in LDS, coalesced store ----------------
  const float* be = bias + (size_t)e * N;
#pragma unroll
  for (int i = 0; i < 4; ++i) {
    int rbase = wm + i * 16 + (lane >> 4) * 4;
#pragma unroll
    for (int j = 0; j < 4; ++j) {
      int col = wn + j * 16 + (lane & 15);
      float bv = be[n0 + col];
#pragma unroll
      for (int r2 = 0; r2 < 4; ++r2) {
        float xv = acc[i][j][r2] + bv;
        if (do_gelu) xv = gelu_tanh(xv);
        *(unsigned short*)(smem + (rbase + r2) * 256 + col * 2) = f2bf(xv);
      }
    }
  }
  __syncthreads();
  const int r16 = tid >> 4, c16 = tid & 15;
#pragma unroll
  for (int it = 0; it < 8; ++it) {
    int row = it * 16 + r16;
    ushort8 v = *(const ushort8*)(smem + row * 256 + c16 * 16);
    *(ushort8*)(Cout + ((size_t)e * M + m0 + row) * N + n0 + c16 * 8) = v;
  }
}

// --------------- Combine: y[t] = sum_k w_k * Ebuf[dest_k] -------------------
__global__ __launch_bounds__(256) void combine_kernel(
    const unsigned short* __restrict__ Ebuf,
    const int* __restrict__ pair_dest,
    const float* __restrict__ pair_w,
    float* __restrict__ out) {
  int t = blockIdx.x;
  int d0 = threadIdx.x * 4;
  float4 r = {0.f, 0.f, 0.f, 0.f};
#pragma unroll
  for (int k = 0; k < 2; ++k) {
    int dest = pair_dest[t * 2 + k];
    if (dest < NE * NCAP) {
      float w = pair_w[t * 2 + k];
      ushort4 v = *(const ushort4*)(Ebuf + (size_t)dest * D_MODEL + d0);
      r.x += w * bf2f(v.x); r.y += w * bf2f(v.y);
      r.z += w * bf2f(v.z); r.w += w * bf2f(v.w);
    }
  }
  *(float4*)(out + (size_t)t * D_MODEL + d0) = r;
}

// ---------------------------------------------------------------------------
extern "C" void kernel_launch(void* const* d_in, const int* in_sizes, int n_in,
                              void* d_out, int out_size, void* d_ws, size_t ws_size,
                              hipStream_t stream) {
  const float* x  = (const float*)d_in[0];
  const float* Wr = (const float*)d_in[1];
  const float* W1 = (const float*)d_in[2];
  const float* b1 = (const float*)d_in[3];
  const float* W2 = (const float*)d_in[4];
  const float* b2 = (const float*)d_in[5];
  float* out = (float*)d_out;

  char* ws = (char*)d_ws;
  unsigned short* W1T  = (unsigned short*)(ws + 0);            // 64 MB
  unsigned short* W2T  = (unsigned short*)(ws + 67108864);     // 64 MB
  unsigned short* Xd   = (unsigned short*)(ws + 134217728);    // 40 MB
  unsigned short* Ebuf = Xd;   // aliased: Xd dead after GEMM1
  unsigned short* Hbuf = (unsigned short*)(ws + 176160768);    // 160 MB
  int*   pair_e    = (int*)(ws + 343932928);
  float* pair_w    = (float*)(ws + 343998464);
  int*   pair_dest = (int*)(ws + 344064000);
  int*   counts    = (int*)(ws + 344129536);

  // W1 [E][D][H] -> W1T [E][H][D]; W2 [E][H][D] -> W2T [E][D][H]
  transpose_cvt<<<dim3(H_DIM / 64, D_MODEL / 64, NE), 256, 0, stream>>>(W1, W1T, D_MODEL, H_DIM);
  transpose_cvt<<<dim3(D_MODEL / 64, H_DIM / 64, NE), 256, 0, stream>>>(W2, W2T, H_DIM, D_MODEL);

  router_kernel<<<NTOK / 4, 256, 0, stream>>>(x, Wr, pair_e, pair_w);
  assign_kernel<<<1, 1024, 0, stream>>>(pair_e, pair_dest, counts);
  dispatch_kernel<<<NPAIR, 64, 0, stream>>>(x, pair_dest, Xd);

  // GEMM1: h = gelu(Xd @ W1 + b1)   M=CAP N=H K=D
  moe_gemm<<<dim3((NCAP / 128) * (H_DIM / 128), 1, NE), 256, 0, stream>>>(
      Xd, W1T, b1, Hbuf, counts, NCAP, H_DIM, D_MODEL, NCAP / 128, 1);
  // GEMM2: Ebuf = h @ W2 + b2       M=CAP N=D K=H
  moe_gemm<<<dim3((NCAP / 128) * (D_MODEL / 128), 1, NE), 256, 0, stream>>>(
      Hbuf, W2T, b2, Ebuf, counts, NCAP, D_MODEL, H_DIM, NCAP / 128, 0);

  combine_kernel<<<NTOK, 256, 0, stream>>>(Ebuf, pair_dest, pair_w, out);
}